// Round 1
// baseline (642.063 us; speedup 1.0000x reference)
//
#include <hip/hip_runtime.h>
#include <cstdint>
#include <cstddef>

#define BATCH 256
#define ED 128
#define NC 32
#define HO 6
#define WO 14
#define FEAT 2688          // 32*6*14
#define HID 256
#define NE 40943
#define EPS 1e-5f
#define W2COLS 344064      // FEAT*128

typedef __attribute__((ext_vector_type(4))) float f32x4;
typedef __attribute__((ext_vector_type(8))) short short8;

__device__ __forceinline__ ushort f2bf(float f) {
    uint32_t u = __builtin_bit_cast(uint32_t, f);
    u = (u + 0x7FFFu + ((u >> 16) & 1u)) >> 16;
    return (ushort)u;
}

// ---------------- K0: bn0 stats (global mean/var of gathered E1) -----------
__global__ void k0_bn0(const int* __restrict__ e1, const float* __restrict__ emb,
                       float* __restrict__ stats) {
    __shared__ float s1[1024], s2[1024];
    int t = threadIdx.x;
    int i = t >> 2, p = (t & 3) * 32;
    const float* row = emb + (size_t)e1[i] * ED + p;
    float a = 0.f, b = 0.f;
#pragma unroll
    for (int q = 0; q < 32; ++q) { float v = row[q]; a += v; b += v * v; }
    s1[t] = a; s2[t] = b;
    __syncthreads();
    for (int s = 512; s > 0; s >>= 1) {
        if (t < s) { s1[t] += s1[t + s]; s2[t] += s2[t + s]; }
        __syncthreads();
    }
    if (t == 0) {
        float m = s1[0] / 32768.f;
        float v = s2[0] / 32768.f - m * m;
        stats[0] = m;
        stats[1] = rsqrtf(v + EPS);
    }
}

// ---------------- K1: CPG hidden layers H[head][i][u] = relu(R@w1) ---------
__global__ void k1_hidden(const int* __restrict__ r, const float* __restrict__ rel,
                          const float* __restrict__ w1a, const float* __restrict__ w1b,
                          const float* __restrict__ w1c, const float* __restrict__ w1d,
                          float* __restrict__ H) {
    int head = blockIdx.x >> 8;
    int i = blockIdx.x & 255;
    int u = threadIdx.x;           // 256 threads
    __shared__ float R[128];
    if (u < 128) R[u] = rel[(size_t)r[i] * 128 + u];
    __syncthreads();
    const float* w1 = head == 0 ? w1a : head == 1 ? w1b : head == 2 ? w1c : w1d;
    float acc = 0.f;
#pragma unroll 8
    for (int d = 0; d < 128; ++d) acc += R[d] * w1[d * 256 + u];
    H[((size_t)head * 256 + i) * 256 + u] = fmaxf(acc, 0.f);
}

// ---------------- K2: small CPG head outputs (filt, cbias, fcb) ------------
__global__ void k2_heads(const float* __restrict__ H,
                         const float* __restrict__ w2f, const float* __restrict__ w2b,
                         const float* __restrict__ w2fcb,
                         float* __restrict__ filt, float* __restrict__ cbias,
                         float* __restrict__ fcb) {
    int i = blockIdx.x;
    int t = threadIdx.x;           // 512 threads
    __shared__ float h0[256], h1[256], h3[256];
    if (t < 256) {
        h0[t] = H[(size_t)(0 * 256 + i) * 256 + t];
        h1[t] = H[(size_t)(1 * 256 + i) * 256 + t];
        h3[t] = H[(size_t)(3 * 256 + i) * 256 + t];
    }
    __syncthreads();
    if (t < 288) {
        float a = 0.f;
#pragma unroll 8
        for (int u = 0; u < 256; ++u) a += h0[u] * w2f[u * 288 + t];
        filt[i * 288 + t] = a;
    } else if (t < 320) {
        int c = t - 288;
        float a = 0.f;
#pragma unroll 8
        for (int u = 0; u < 256; ++u) a += h1[u] * w2b[u * 32 + c];
        cbias[i * 32 + c] = a;
    } else if (t < 448) {
        int c = t - 320;
        float a = 0.f;
#pragma unroll 8
        for (int u = 0; u < 256; ++u) a += h3[u] * w2fcb[u * 128 + c];
        fcb[i * 128 + c] = a;
    }
}

// ---------------- K3: per-sample conv + bias + relu -> Xc (bf16) -----------
__global__ void k3_conv(const int* __restrict__ e1, const float* __restrict__ emb,
                        const float* __restrict__ stats, const float* __restrict__ filt,
                        const float* __restrict__ cbias, ushort* __restrict__ Xc) {
    int i = blockIdx.x, t = threadIdx.x;   // 256 threads
    __shared__ float x[128], f[288], cb[32];
    float mean = stats[0], rstd = stats[1];
    if (t < 128) x[t] = (emb[(size_t)e1[i] * 128 + t] - mean) * rstd;
    if (t < 32) cb[t] = cbias[i * 32 + t];
    for (int o = t; o < 288; o += 256) f[o] = filt[i * 288 + o];
    __syncthreads();
    for (int o = t; o < FEAT; o += 256) {
        int c = o / 84, rem = o % 84;      // 84 = 6*14
        int y = rem / 14, xw = rem % 14;
        float acc = cb[c];
        const float* fc = &f[c * 9];
#pragma unroll
        for (int dy = 0; dy < 3; ++dy)
#pragma unroll
            for (int dx = 0; dx < 3; ++dx)
                acc += x[(y + dy) * 16 + (xw + dx)] * fc[dy * 3 + dx];
        Xc[(size_t)i * FEAT + o] = f2bf(fmaxf(acc, 0.f));
    }
}

// ---------------- K4: big batched GEMM  T[h,i,k] = sum_j Xc[i,j]*W2[h,j,k] --
// one block per h (256 blocks); W2 row streamed from HBM exactly once.
__global__ __launch_bounds__(512, 2) void k4_gemm(const ushort* __restrict__ Xc,
                                                  const float* __restrict__ W2,
                                                  float* __restrict__ T) {
    int h = blockIdx.x;
    int tid = threadIdx.x, lane = tid & 63, wave = tid >> 6;   // 8 waves
    int l15 = lane & 15, l4 = lane >> 4;
    __shared__ __align__(16) ushort Bt[128 * 40];   // [k=128][j=32 +8 pad] bf16, transposed
    const float* Brow = W2 + (size_t)h * W2COLS;

    int kk = tid & 127;        // k index this thread stages
    int jg = tid >> 7;         // j-group (0..3): j_rel = jg*8..+8

    f32x4 acc[2][8];
#pragma unroll
    for (int mt = 0; mt < 2; ++mt)
#pragma unroll
        for (int nt = 0; nt < 8; ++nt)
#pragma unroll
            for (int q = 0; q < 4; ++q) acc[mt][nt][q] = 0.f;

    // prefetch K-step 0 into registers
    float p[8];
#pragma unroll
    for (int q = 0; q < 8; ++q) p[q] = Brow[(size_t)(jg * 8 + q) * 128 + kk];

    for (int s = 0; s < 84; ++s) {
        __syncthreads();               // previous step's LDS consumers done
        short8 w8;
#pragma unroll
        for (int q = 0; q < 8; ++q) w8[q] = (short)f2bf(p[q]);
        *(short8*)&Bt[kk * 40 + jg * 8] = w8;   // conflict-free (stride 40)
        __syncthreads();
        if (s + 1 < 84) {
            int j0n = (s + 1) * 32;
#pragma unroll
            for (int q = 0; q < 8; ++q)
                p[q] = Brow[(size_t)(j0n + jg * 8 + q) * 128 + kk];
        }
        int j0 = s * 32;
        short8 bf[8];
#pragma unroll
        for (int nt = 0; nt < 8; ++nt)
            bf[nt] = *(const short8*)&Bt[(nt * 16 + l15) * 40 + l4 * 8];
        short8 af[2];
#pragma unroll
        for (int mt = 0; mt < 2; ++mt) {
            int i = wave * 32 + mt * 16 + l15;
            af[mt] = *(const short8*)(Xc + (size_t)i * FEAT + j0 + l4 * 8);
        }
#pragma unroll
        for (int mt = 0; mt < 2; ++mt)
#pragma unroll
            for (int nt = 0; nt < 8; ++nt)
                acc[mt][nt] = __builtin_amdgcn_mfma_f32_16x16x32_bf16(
                    af[mt], bf[nt], acc[mt][nt], 0, 0, 0);
    }
    // store T[h][i][k]
#pragma unroll
    for (int mt = 0; mt < 2; ++mt)
#pragma unroll
        for (int nt = 0; nt < 8; ++nt) {
            int row0 = wave * 32 + mt * 16 + l4 * 4;
            int col = nt * 16 + l15;
#pragma unroll
            for (int rr = 0; rr < 4; ++rr)
                T[((size_t)h * 256 + row0 + rr) * 128 + col] = acc[mt][nt][rr];
        }
}

// ---------------- K5: X[i,k] = fcb[i,k] + sum_h Hfc[i,h]*T[h,i,k] ----------
__global__ void k5_stage2(const float* __restrict__ T, const float* __restrict__ Hfc,
                          const float* __restrict__ fcb, float* __restrict__ X) {
    int i = blockIdx.x, k = threadIdx.x;   // 128 threads
    const float* hp = Hfc + (size_t)i * 256;
    const float* tp = T + (size_t)i * 128 + k;
    float acc = fcb[i * 128 + k];
#pragma unroll 8
    for (int h = 0; h < 256; ++h) acc += hp[h] * tp[(size_t)h * 32768];
    X[i * 128 + k] = acc;
}

// ---------------- K6: bn2 (per-column over batch) + relu -> Xn (bf16) ------
__global__ void k6_bn2(const float* __restrict__ X, ushort* __restrict__ Xn) {
    int k = blockIdx.x;      // 128 blocks: one per column
    int i = threadIdx.x;     // 256 threads: one per row
    __shared__ float s1[256], s2[256];
    float v = X[i * 128 + k];
    s1[i] = v; s2[i] = v * v;
    __syncthreads();
    for (int s = 128; s > 0; s >>= 1) {
        if (i < s) { s1[i] += s1[i + s]; s2[i] += s2[i + s]; }
        __syncthreads();
    }
    float m = s1[0] / 256.f;
    float var = s2[0] / 256.f - m * m;
    float rstd = rsqrtf(var + EPS);
    Xn[i * 128 + k] = f2bf(fmaxf((v - m) * rstd, 0.f));
}

// ---------------- K7: out = sigmoid(Xn @ E2^T + b) -------------------------
__global__ __launch_bounds__(256) void k7_final(const ushort* __restrict__ Xn,
                                                const float* __restrict__ E2,
                                                const float* __restrict__ bias,
                                                float* __restrict__ out) {
    int eb = blockIdx.x * 64;
    int lane = threadIdx.x & 63, wave = threadIdx.x >> 6;
    int l15 = lane & 15, l4 = lane >> 4;
    int i0 = wave * 64;

    f32x4 acc[4][4];
#pragma unroll
    for (int mt = 0; mt < 4; ++mt)
#pragma unroll
        for (int nt = 0; nt < 4; ++nt)
#pragma unroll
            for (int q = 0; q < 4; ++q) acc[mt][nt][q] = 0.f;

#pragma unroll
    for (int ks = 0; ks < 4; ++ks) {
        int k0 = ks * 32 + l4 * 8;
        short8 a[4];
#pragma unroll
        for (int mt = 0; mt < 4; ++mt) {
            int i = i0 + mt * 16 + l15;
            a[mt] = *(const short8*)(Xn + (size_t)i * 128 + k0);
        }
        short8 b[4];
#pragma unroll
        for (int nt = 0; nt < 4; ++nt) {
            int e = eb + nt * 16 + l15;
            int ec = e < NE ? e : NE - 1;
            const float* rp = E2 + (size_t)ec * 128 + k0;
            short8 tv;
#pragma unroll
            for (int q = 0; q < 8; ++q) tv[q] = (short)f2bf(rp[q]);
            b[nt] = tv;
        }
#pragma unroll
        for (int mt = 0; mt < 4; ++mt)
#pragma unroll
            for (int nt = 0; nt < 4; ++nt)
                acc[mt][nt] = __builtin_amdgcn_mfma_f32_16x16x32_bf16(
                    a[mt], b[nt], acc[mt][nt], 0, 0, 0);
    }
#pragma unroll
    for (int nt = 0; nt < 4; ++nt) {
        int e = eb + nt * 16 + l15;
        bool ok = e < NE;
        float bb = bias[e < NE ? e : NE - 1];
#pragma unroll
        for (int mt = 0; mt < 4; ++mt) {
            int row0 = i0 + mt * 16 + l4 * 4;
#pragma unroll
            for (int rr = 0; rr < 4; ++rr) {
                float v = acc[mt][nt][rr] + bb;
                float sg = 1.f / (1.f + __expf(-v));
                if (ok) out[(size_t)(row0 + rr) * NE + e] = sg;
            }
        }
    }
}

extern "C" void kernel_launch(void* const* d_in, const int* in_sizes, int n_in,
                              void* d_out, int out_size, void* d_ws, size_t ws_size,
                              hipStream_t stream) {
    const int* e1 = (const int*)d_in[0];
    const int* r = (const int*)d_in[1];
    const float* emb = (const float*)d_in[2];
    const float* rel = (const float*)d_in[3];
    const float* convw_w1 = (const float*)d_in[4];
    const float* convw_w2 = (const float*)d_in[5];
    const float* convb_w1 = (const float*)d_in[6];
    const float* convb_w2 = (const float*)d_in[7];
    const float* fcw_w1 = (const float*)d_in[8];
    const float* fcw_w2 = (const float*)d_in[9];
    const float* fcb_w1 = (const float*)d_in[10];
    const float* fcb_w2 = (const float*)d_in[11];
    const float* bvec = (const float*)d_in[12];
    float* out = (float*)d_out;

    char* ws = (char*)d_ws;
    float* stats = (float*)(ws + 0);            // 2 floats
    float* H = (float*)(ws + 256);              // [4][256][256] f32
    float* filt = (float*)(ws + 1048832);       // [256][288] f32
    float* cbias = (float*)(ws + 1343744);      // [256][32] f32
    float* fcbv = (float*)(ws + 1376512);       // [256][128] f32
    ushort* Xc = (ushort*)(ws + 1507584);       // [256][2688] bf16
    float* T = (float*)(ws + 2883840);          // [256][256][128] f32 (33.5 MB)
    float* X = (float*)(ws + 36438272);         // [256][128] f32
    ushort* Xn = (ushort*)(ws + 36569344);      // [256][128] bf16

    k0_bn0<<<1, 1024, 0, stream>>>(e1, emb, stats);
    k1_hidden<<<1024, 256, 0, stream>>>(r, rel, convw_w1, convb_w1, fcw_w1, fcb_w1, H);
    k2_heads<<<256, 512, 0, stream>>>(H, convw_w2, convb_w2, fcb_w2, filt, cbias, fcbv);
    k3_conv<<<256, 256, 0, stream>>>(e1, emb, stats, filt, cbias, Xc);
    k4_gemm<<<256, 512, 0, stream>>>(Xc, fcw_w2, T);
    k5_stage2<<<256, 128, 0, stream>>>(T, H + 2 * 65536, fcbv, X);
    k6_bn2<<<128, 256, 0, stream>>>(X, Xn);
    k7_final<<<640, 256, 0, stream>>>(Xn, emb, bvec, out);
}